// Round 10
// baseline (387.425 us; speedup 1.0000x reference)
//
#include <hip/hip_runtime.h>
#include <hip/hip_bf16.h>

#define NN 100000
#define NE 1600000
#define NB 391       // buckets of 256 nodes: (100000 + 255) >> 8
#define CHUNK 4096   // edges per scatter block
#define NBLK 391     // ceil(NE / CHUNK)

typedef short bf8v __attribute__((ext_vector_type(8)));   // 8 bf16 (4 VGPRs)
typedef float f32x4 __attribute__((ext_vector_type(4)));  // MFMA acc

static __device__ __forceinline__ float lrelu(float x, float s) {
    return x > 0.f ? x : s * x;
}

static __device__ __forceinline__ unsigned short f2b(float f) {
    __hip_bfloat16 b = __float2bfloat16(f);
    return *reinterpret_cast<unsigned short*>(&b);
}

static __device__ __forceinline__ float blo(unsigned u) {
    return __uint_as_float(u << 16);
}
static __device__ __forceinline__ float bhi(unsigned u) {
    return __uint_as_float(u & 0xFFFF0000u);
}

struct alignas(4) bh2 {
    __hip_bfloat16 x, y;
};

// ---------------- CSR build: atomic-free two-level counting sort ----------------
// part entries packed as (dst&255)<<24 | src  (src < 2^17 -> fits 24 bits)

// per-chunk histogram -> histmat[blk*NB + bucket]  (no global atomics)
__global__ __launch_bounds__(256) void csr_count(const int* __restrict__ dsts,
                                                 int* __restrict__ histmat) {
    __shared__ int hist[NB];
    for (int t = threadIdx.x; t < NB; t += 256) hist[t] = 0;
    __syncthreads();
    int e0 = blockIdx.x * CHUNK;
#pragma unroll
    for (int k = 0; k < CHUNK / 256; k++) {
        int e = e0 + k * 256 + threadIdx.x;
        if (e < NE) atomicAdd(&hist[dsts[e] >> 8], 1);
    }
    __syncthreads();
    for (int t = threadIdx.x; t < NB; t += 256) histmat[blockIdx.x * NB + t] = hist[t];
}

// one block: per-bucket exclusive prefix over chunks (in place), bucket scan -> bbase
__global__ __launch_bounds__(512) void csr_scan(int* __restrict__ histmat,
                                                int* __restrict__ bbase) {
    __shared__ int sd[512];
    int t = threadIdx.x;
    int run = 0;
    if (t < NB) {
        for (int blk = 0; blk < NBLK; ++blk) {
            int idx = blk * NB + t;
            int v = histmat[idx];
            histmat[idx] = run;  // exclusive prefix of bucket t over chunks
            run += v;
        }
    }
    sd[t] = run;  // total count of bucket t (0 for t >= NB)
    __syncthreads();
    for (int off = 1; off < 512; off <<= 1) {
        int x = (t >= off) ? sd[t - off] : 0;
        __syncthreads();
        sd[t] += x;
        __syncthreads();
    }
    int excl = sd[t] - run;
    if (t < NB) bbase[t] = excl;
    if (t == NB - 1) bbase[NB] = excl + run;
}

// each chunk writes part[] into its reserved per-bucket ranges (LDS cursors only)
__global__ __launch_bounds__(256) void csr_scatter(const int* __restrict__ srcs,
                                                   const int* __restrict__ dsts,
                                                   const int* __restrict__ histmat,
                                                   const int* __restrict__ bbase,
                                                   unsigned* __restrict__ part) {
    __shared__ int cur[NB];
    int blk = blockIdx.x;
    for (int t = threadIdx.x; t < NB; t += 256)
        cur[t] = bbase[t] + histmat[blk * NB + t];
    __syncthreads();
    int e0 = blk * CHUNK;
#pragma unroll
    for (int k = 0; k < CHUNK / 256; k++) {
        int e = e0 + k * 256 + threadIdx.x;
        if (e < NE) {
            int s = srcs[e], d = dsts[e];
            int r = atomicAdd(&cur[d >> 8], 1);
            part[r] = (((unsigned)d & 255u) << 24) | (unsigned)s;
        }
    }
}

__global__ __launch_bounds__(256) void bucket_fill(const unsigned* __restrict__ part,
                                                   const int* __restrict__ bbase,
                                                   int* __restrict__ offs,
                                                   int* __restrict__ csr) {
    __shared__ int lcur[256];
    __shared__ int sd[256];
    int b = blockIdx.x;
    int t = threadIdx.x;
    int ebeg = bbase[b], eend = bbase[b + 1];
    int node0 = b << 8;
    int nNodes = min(256, NN - node0);
    lcur[t] = 0;
    __syncthreads();
    for (int e = ebeg + t; e < eend; e += 256) {
        unsigned p = part[e];
        atomicAdd(&lcur[p >> 24], 1);
    }
    __syncthreads();
    int cnt = lcur[t];
    sd[t] = cnt;
    __syncthreads();
    for (int off = 1; off < 256; off <<= 1) {
        int x = (t >= off) ? sd[t - off] : 0;
        __syncthreads();
        sd[t] += x;
        __syncthreads();
    }
    int start = ebeg + sd[t] - cnt;
    if (t < nNodes) offs[node0 + t] = start;
    if (b == NB - 1 && t == 0) offs[NN] = NE;
    lcur[t] = start;
    __syncthreads();
    for (int e = ebeg + t; e < eend; e += 256) {
        unsigned p = part[e];
        int pos = atomicAdd(&lcur[p >> 24], 1);
        csr[pos] = (int)(p & 0xFFFFFFu);
    }
}

// ---------------- fused MFMA GEMM + attention coefficients ----------------

template <int NOUT, int HEADS, bool AF32>
__global__ __launch_bounds__(256) void gemm_fused(
    const float* __restrict__ A32, const unsigned short* __restrict__ A16,
    const float* __restrict__ W, const float* __restrict__ asrc,
    const float* __restrict__ adst, unsigned short* __restrict__ h16out,
    float* __restrict__ als, float* __restrict__ ald, int n) {
    constexpr int NF = NOUT / 16;
    constexpr int PITCH = 136;
    __shared__ unsigned short Wl[NOUT * PITCH];

    const int tid = threadIdx.x;
    for (int i = tid; i < (128 * NOUT) / 4; i += 256) {
        int idx = i * 4;
        int k = idx / NOUT;
        int c = idx - k * NOUT;
        float4 wv = *(const float4*)&W[idx];
        Wl[(c + 0) * PITCH + k] = f2b(wv.x);
        Wl[(c + 1) * PITCH + k] = f2b(wv.y);
        Wl[(c + 2) * PITCH + k] = f2b(wv.z);
        Wl[(c + 3) * PITCH + k] = f2b(wv.w);
    }
    __syncthreads();

    const int lane = tid & 63, wave = tid >> 6;
    const int c = lane & 15, hi = lane >> 4;
    const int r0 = blockIdx.x * 64;
    const int arow = min(r0 + wave * 16 + c, n - 1);
    const int kb = hi * 8;

    f32x4 acc[NF];
#pragma unroll
    for (int nf = 0; nf < NF; ++nf) acc[nf] = 0;

#pragma unroll
    for (int kc = 0; kc < 4; ++kc) {
        bf8v a;
        if constexpr (AF32) {
            const float* ap = A32 + (size_t)arow * 128 + kc * 32 + kb;
            float4 f0 = *(const float4*)ap;
            float4 f1 = *(const float4*)(ap + 4);
            union {
                bf8v v;
                unsigned short u[8];
            } ua;
            ua.u[0] = f2b(f0.x);
            ua.u[1] = f2b(f0.y);
            ua.u[2] = f2b(f0.z);
            ua.u[3] = f2b(f0.w);
            ua.u[4] = f2b(f1.x);
            ua.u[5] = f2b(f1.y);
            ua.u[6] = f2b(f1.z);
            ua.u[7] = f2b(f1.w);
            a = ua.v;
        } else {
            a = *(const bf8v*)(A16 + (size_t)arow * 128 + kc * 32 + kb);
        }
#pragma unroll
        for (int nf = 0; nf < NF; ++nf) {
            bf8v b = *(const bf8v*)&Wl[(nf * 16 + c) * PITCH + kc * 32 + kb];
            acc[nf] = __builtin_amdgcn_mfma_f32_16x16x32_bf16(a, b, acc[nf], 0, 0, 0);
        }
    }

    // epilogue 1: als/ald from accumulators
    float aS[NF], aD[NF];
#pragma unroll
    for (int nf = 0; nf < NF; ++nf) {
        aS[nf] = asrc[nf * 16 + c];
        aD[nf] = adst[nf * 16 + c];
    }
    float sRes[HEADS][4], dRes[HEADS][4];
#pragma unroll
    for (int hh = 0; hh < HEADS; ++hh) {
#pragma unroll
        for (int reg = 0; reg < 4; ++reg) {
            float s = 0.f, d = 0.f;
#pragma unroll
            for (int nf = hh * (NF / HEADS); nf < (hh + 1) * (NF / HEADS); ++nf) {
                s += acc[nf][reg] * aS[nf];
                d += acc[nf][reg] * aD[nf];
            }
#pragma unroll
            for (int o = 1; o < 16; o <<= 1) {
                s += __shfl_xor(s, o);
                d += __shfl_xor(d, o);
            }
            sRes[hh][reg] = s;
            dRes[hh][reg] = d;
        }
    }
    if (c == 0) {
#pragma unroll
        for (int reg = 0; reg < 4; ++reg) {
            int ro = r0 + wave * 16 + hi * 4 + reg;
            if (ro < n) {
                if constexpr (HEADS == 4) {
                    *(float4*)&als[ro * 4] =
                        make_float4(sRes[0][reg], sRes[1][reg], sRes[2][reg], sRes[3][reg]);
                    *(float4*)&ald[ro * 4] =
                        make_float4(dRes[0][reg], dRes[1][reg], dRes[2][reg], dRes[3][reg]);
                } else {
                    als[ro] = sRes[0][reg];
                    ald[ro] = dRes[0][reg];
                }
            }
        }
    }

    // epilogue 2: h -> bf16 via LDS transpose, coalesced store
    __syncthreads();
#pragma unroll
    for (int nf = 0; nf < NF; ++nf) {
#pragma unroll
        for (int reg = 0; reg < 4; ++reg) {
            int rl = wave * 16 + hi * 4 + reg;
            Wl[rl * PITCH + nf * 16 + c] = f2b(acc[nf][reg]);
        }
    }
    __syncthreads();
    constexpr int SEGS = NOUT / 8;
    for (int i = tid; i < 64 * SEGS; i += 256) {
        int rl = i / SEGS, sg = i - rl * SEGS;
        int ro = r0 + rl;
        if (ro < n)
            *(uint4*)&h16out[(size_t)ro * NOUT + sg * 8] =
                *(const uint4*)&Wl[rl * PITCH + sg * 8];
    }
}

// ---------------- GAT aggregation, 4 heads (F=128), wave per dst node ----------------
// Full-wave dword gather (one 256B row per instruction), 8 loads in flight.
// Lane owns feats (2*lane, 2*lane+1); head = lane>>4.

__global__ __launch_bounds__(256) void agg4_kernel(
    const char* __restrict__ hb, const float* __restrict__ als, const float* __restrict__ ald,
    const int* __restrict__ offs, const int* __restrict__ cur, const int* __restrict__ csr,
    const float* __restrict__ bias, __hip_bfloat16* __restrict__ out, int n, int do_l1) {
    __shared__ int soff[4][64];
    __shared__ float sp[4][64][4];
    int w = threadIdx.x >> 6;
    int v = blockIdx.x * 4 + w;
    if (v >= n) return;
    int lane = threadIdx.x & 63;
    int hd = lane >> 4;
    int lane4 = lane << 2;

    float4 av = *(const float4*)&ald[v * 4];
    float4 svv = *(const float4*)&als[v * 4];
    int begin = offs[v], end = cur[v];

    float ps0 = __expf(lrelu(svv.x + av.x, 0.2f));
    float ps1 = __expf(lrelu(svv.y + av.y, 0.2f));
    float ps2 = __expf(lrelu(svv.z + av.z, 0.2f));
    float ps3 = __expf(lrelu(svv.w + av.w, 0.2f));
    float psel = hd == 0 ? ps0 : hd == 1 ? ps1 : hd == 2 ? ps2 : ps3;
    unsigned uv = *(const unsigned*)(hb + (size_t)v * 256 + lane4);
    float acc0 = psel * blo(uv);
    float acc1 = psel * bhi(uv);
    float s0 = 0.f, s1 = 0.f, s2 = 0.f, s3 = 0.f;

    for (int base = begin; base < end; base += 64) {
        int idx = base + lane;
        int cnt = min(64, end - base);
        if (idx < end) {
            int s = csr[idx];
            float4 q = *(const float4*)&als[s * 4];
            float p0 = __expf(lrelu(q.x + av.x, 0.2f));
            float p1 = __expf(lrelu(q.y + av.y, 0.2f));
            float p2 = __expf(lrelu(q.z + av.z, 0.2f));
            float p3 = __expf(lrelu(q.w + av.w, 0.2f));
            soff[w][lane] = s << 8;  // byte offset into bf16 rows (128*2B)
            sp[w][lane][0] = p0;
            sp[w][lane][1] = p1;
            sp[w][lane][2] = p2;
            sp[w][lane][3] = p3;
            s0 += p0; s1 += p1; s2 += p2; s3 += p3;
        }
        asm volatile("s_waitcnt lgkmcnt(0)" ::: "memory");
        int t = 0;
        for (; t + 8 <= cnt; t += 8) {
            int o0 = soff[w][t + 0], o1 = soff[w][t + 1];
            int o2 = soff[w][t + 2], o3 = soff[w][t + 3];
            int o4 = soff[w][t + 4], o5 = soff[w][t + 5];
            int o6 = soff[w][t + 6], o7 = soff[w][t + 7];
            float p0 = sp[w][t + 0][hd], p1 = sp[w][t + 1][hd];
            float p2 = sp[w][t + 2][hd], p3 = sp[w][t + 3][hd];
            float p4 = sp[w][t + 4][hd], p5 = sp[w][t + 5][hd];
            float p6 = sp[w][t + 6][hd], p7 = sp[w][t + 7][hd];
            unsigned u0 = *(const unsigned*)(hb + o0 + lane4);
            unsigned u1 = *(const unsigned*)(hb + o1 + lane4);
            unsigned u2 = *(const unsigned*)(hb + o2 + lane4);
            unsigned u3 = *(const unsigned*)(hb + o3 + lane4);
            unsigned u4 = *(const unsigned*)(hb + o4 + lane4);
            unsigned u5 = *(const unsigned*)(hb + o5 + lane4);
            unsigned u6 = *(const unsigned*)(hb + o6 + lane4);
            unsigned u7 = *(const unsigned*)(hb + o7 + lane4);
            acc0 += p0 * blo(u0);
            acc1 += p0 * bhi(u0);
            acc0 += p1 * blo(u1);
            acc1 += p1 * bhi(u1);
            acc0 += p2 * blo(u2);
            acc1 += p2 * bhi(u2);
            acc0 += p3 * blo(u3);
            acc1 += p3 * bhi(u3);
            acc0 += p4 * blo(u4);
            acc1 += p4 * bhi(u4);
            acc0 += p5 * blo(u5);
            acc1 += p5 * bhi(u5);
            acc0 += p6 * blo(u6);
            acc1 += p6 * bhi(u6);
            acc0 += p7 * blo(u7);
            acc1 += p7 * bhi(u7);
        }
        for (; t < cnt; ++t) {
            int oa = soff[w][t];
            float pa = sp[w][t][hd];
            unsigned ua = *(const unsigned*)(hb + oa + lane4);
            acc0 += pa * blo(ua);
            acc1 += pa * bhi(ua);
        }
    }
#pragma unroll
    for (int o = 32; o > 0; o >>= 1) {
        s0 += __shfl_xor(s0, o);
        s1 += __shfl_xor(s1, o);
        s2 += __shfl_xor(s2, o);
        s3 += __shfl_xor(s3, o);
    }
    s0 += ps0; s1 += ps1; s2 += ps2; s3 += ps3;
    float ssel = hd == 0 ? s0 : hd == 1 ? s1 : hd == 2 ? s2 : s3;
    float inv = 1.f / (ssel + 1e-16f);
    float2 bv = *(const float2*)&bias[2 * lane];
    float o0 = lrelu(acc0 * inv + bv.x, 0.01f);
    float o1 = lrelu(acc1 * inv + bv.y, 0.01f);
    if (do_l1) {
        float t = fabsf(o0) + fabsf(o1);
#pragma unroll
        for (int o = 32; o > 0; o >>= 1) t += __shfl_xor(t, o);
        float li = 1.f / fmaxf(t, 1e-12f);
        o0 *= li;
        o1 *= li;
    }
    bh2 pk;
    pk.x = __float2bfloat16(o0);
    pk.y = __float2bfloat16(o1);
    *(bh2*)&out[(size_t)v * 128 + 2 * lane] = pk;
}

// ---------------- GAT aggregation, 1 head (F=64), wave per dst node --------

__global__ __launch_bounds__(256) void agg1_kernel(
    const char* __restrict__ hb, const float* __restrict__ als, const float* __restrict__ ald,
    const int* __restrict__ offs, const int* __restrict__ cur, const int* __restrict__ csr,
    const float* __restrict__ bias, float* __restrict__ out, int n) {
    __shared__ int soff[4][64];
    __shared__ float sp[4][64];
    int w = threadIdx.x >> 6;
    int v = blockIdx.x * 4 + w;
    if (v >= n) return;
    int lane = threadIdx.x & 63;
    int lane2 = lane << 1;
    float aldv = ald[v];
    float alsv = als[v];
    int begin = offs[v], end = cur[v];

    float pself = __expf(lrelu(alsv + aldv, 0.2f));
    unsigned short usv = *(const unsigned short*)(hb + (size_t)v * 128 + lane2);
    float acc = pself * __uint_as_float(((unsigned)usv) << 16);
    float ssum = 0.f;

    for (int base = begin; base < end; base += 64) {
        int idx = base + lane;
        int cnt = min(64, end - base);
        if (idx < end) {
            int s = csr[idx];
            float p = __expf(lrelu(als[s] + aldv, 0.2f));
            soff[w][lane] = s << 7;  // byte offset into bf16 rows (64*2B)
            sp[w][lane] = p;
            ssum += p;
        }
        asm volatile("s_waitcnt lgkmcnt(0)" ::: "memory");
        int t = 0;
        for (; t + 8 <= cnt; t += 8) {
            int o0 = soff[w][t + 0], o1 = soff[w][t + 1];
            int o2 = soff[w][t + 2], o3 = soff[w][t + 3];
            int o4 = soff[w][t + 4], o5 = soff[w][t + 5];
            int o6 = soff[w][t + 6], o7 = soff[w][t + 7];
            float p0 = sp[w][t + 0], p1 = sp[w][t + 1];
            float p2 = sp[w][t + 2], p3 = sp[w][t + 3];
            float p4 = sp[w][t + 4], p5 = sp[w][t + 5];
            float p6 = sp[w][t + 6], p7 = sp[w][t + 7];
            unsigned short u0 = *(const unsigned short*)(hb + o0 + lane2);
            unsigned short u1 = *(const unsigned short*)(hb + o1 + lane2);
            unsigned short u2 = *(const unsigned short*)(hb + o2 + lane2);
            unsigned short u3 = *(const unsigned short*)(hb + o3 + lane2);
            unsigned short u4 = *(const unsigned short*)(hb + o4 + lane2);
            unsigned short u5 = *(const unsigned short*)(hb + o5 + lane2);
            unsigned short u6 = *(const unsigned short*)(hb + o6 + lane2);
            unsigned short u7 = *(const unsigned short*)(hb + o7 + lane2);
            acc += p0 * __uint_as_float(((unsigned)u0) << 16);
            acc += p1 * __uint_as_float(((unsigned)u1) << 16);
            acc += p2 * __uint_as_float(((unsigned)u2) << 16);
            acc += p3 * __uint_as_float(((unsigned)u3) << 16);
            acc += p4 * __uint_as_float(((unsigned)u4) << 16);
            acc += p5 * __uint_as_float(((unsigned)u5) << 16);
            acc += p6 * __uint_as_float(((unsigned)u6) << 16);
            acc += p7 * __uint_as_float(((unsigned)u7) << 16);
        }
        for (; t < cnt; ++t) {
            int oa = soff[w][t];
            float pa = sp[w][t];
            unsigned short ua = *(const unsigned short*)(hb + oa + lane2);
            acc += pa * __uint_as_float(((unsigned)ua) << 16);
        }
    }
#pragma unroll
    for (int o = 32; o > 0; o >>= 1) ssum += __shfl_xor(ssum, o);
    ssum += pself;
    float o = acc / (ssum + 1e-16f) + bias[lane];
    float t = fabsf(o);
#pragma unroll
    for (int off = 32; off > 0; off >>= 1) t += __shfl_xor(t, off);
    o = o / fmaxf(t, 1e-12f);
    out[(size_t)v * 64 + lane] = fmaxf(o, 0.f);
}

// ---------------- launch ----------------

extern "C" void kernel_launch(void* const* d_in, const int* in_sizes, int n_in,
                              void* d_out, int out_size, void* d_ws, size_t ws_size,
                              hipStream_t stream) {
    const float* x = (const float*)d_in[0];
    const int* ei = (const int*)d_in[1];
    const float* W0 = (const float*)d_in[2];
    const float* b0 = (const float*)d_in[3];
    const float* as0 = (const float*)d_in[4];
    const float* ad0 = (const float*)d_in[5];
    const float* W1 = (const float*)d_in[6];
    const float* b1 = (const float*)d_in[7];
    const float* as1 = (const float*)d_in[8];
    const float* ad1 = (const float*)d_in[9];
    const float* W2 = (const float*)d_in[10];
    const float* b2 = (const float*)d_in[11];
    const float* as2 = (const float*)d_in[12];
    const float* ad2 = (const float*)d_in[13];
    float* outp = (float*)d_out;

    char* ws = (char*)d_ws;
    size_t off = 0;
    auto alloc = [&](size_t bytes) -> void* {
        void* p = ws + off;
        off = (off + bytes + 255) & ~(size_t)255;
        return p;
    };
    int* offs = (int*)alloc((NN + 1) * 4);
    int* histmat = (int*)alloc((size_t)NBLK * NB * 4);
    int* bbase = (int*)alloc((NB + 1) * 4);
    unsigned* part = (unsigned*)alloc((size_t)NE * 4);
    int* csr = (int*)alloc((size_t)NE * 4);
    unsigned short* h16 = (unsigned short*)alloc((size_t)NN * 128 * 2);
    unsigned short* a16 = (unsigned short*)alloc((size_t)NN * 128 * 2);
    float* als = (float*)alloc(NN * 4 * 4);
    float* ald = (float*)alloc(NN * 4 * 4);

    const int* srcs = ei;
    const int* dsts = ei + NE;

    // CSR build (atomic-free two-phase counting sort)
    csr_count<<<NBLK, 256, 0, stream>>>(dsts, histmat);
    csr_scan<<<1, 512, 0, stream>>>(histmat, bbase);
    csr_scatter<<<NBLK, 256, 0, stream>>>(srcs, dsts, histmat, bbase, part);
    bucket_fill<<<NB, 256, 0, stream>>>(part, bbase, offs, csr);

    int ggrid = (NN + 63) / 64;
    int aggrid = (NN + 3) / 4;

    // layer 0
    gemm_fused<128, 4, true><<<ggrid, 256, 0, stream>>>(x, nullptr, W0, as0, ad0, h16, als, ald,
                                                        NN);
    agg4_kernel<<<aggrid, 256, 0, stream>>>((const char*)h16, als, ald, offs, offs + 1, csr, b0,
                                            (__hip_bfloat16*)a16, NN, 1);
    // layer 1
    gemm_fused<128, 4, false><<<ggrid, 256, 0, stream>>>(nullptr, a16, W1, as1, ad1, h16, als,
                                                         ald, NN);
    agg4_kernel<<<aggrid, 256, 0, stream>>>((const char*)h16, als, ald, offs, offs + 1, csr, b1,
                                            (__hip_bfloat16*)a16, NN, 0);
    // layer 2
    gemm_fused<64, 1, false><<<ggrid, 256, 0, stream>>>(nullptr, a16, W2, as2, ad2, h16, als,
                                                        ald, NN);
    agg1_kernel<<<aggrid, 256, 0, stream>>>((const char*)h16, als, ald, offs, offs + 1, csr, b2,
                                            outp, NN);
}

// Round 11
// 363.246 us; speedup vs baseline: 1.0666x; 1.0666x over previous
//
#include <hip/hip_runtime.h>
#include <hip/hip_bf16.h>

#define NN 100000
#define NE 1600000
#define NB 391       // buckets of 256 nodes: (100000 + 255) >> 8
#define CHUNK 4096   // edges per scatter block
#define NBLK 391     // ceil(NE / CHUNK)

typedef short bf8v __attribute__((ext_vector_type(8)));   // 8 bf16 (4 VGPRs)
typedef float f32x4 __attribute__((ext_vector_type(4)));  // MFMA acc

static __device__ __forceinline__ float lrelu(float x, float s) {
    return x > 0.f ? x : s * x;
}

static __device__ __forceinline__ unsigned short f2b(float f) {
    __hip_bfloat16 b = __float2bfloat16(f);
    return *reinterpret_cast<unsigned short*>(&b);
}

static __device__ __forceinline__ float blo(unsigned u) {
    return __uint_as_float(u << 16);
}
static __device__ __forceinline__ float bhi(unsigned u) {
    return __uint_as_float(u & 0xFFFF0000u);
}

struct alignas(4) bh2 {
    __hip_bfloat16 x, y;
};

// ---------------- CSR build: atomic-free two-level counting sort ----------------
// part entries packed as (dst&255)<<24 | src  (src < 2^17 -> fits 24 bits)

// per-chunk histogram -> histmat[blk*NB + bucket]  (no global atomics)
__global__ __launch_bounds__(256) void csr_count(const int* __restrict__ dsts,
                                                 int* __restrict__ histmat) {
    __shared__ int hist[NB];
    for (int t = threadIdx.x; t < NB; t += 256) hist[t] = 0;
    __syncthreads();
    int e0 = blockIdx.x * CHUNK;
#pragma unroll
    for (int k = 0; k < CHUNK / 256; k++) {
        int e = e0 + k * 256 + threadIdx.x;
        if (e < NE) atomicAdd(&hist[dsts[e] >> 8], 1);
    }
    __syncthreads();
    for (int t = threadIdx.x; t < NB; t += 256) histmat[blockIdx.x * NB + t] = hist[t];
}

// block b: exclusive prefix of bucket b's counts over chunks (in place), total -> btot[b]
__global__ __launch_bounds__(256) void csr_scan_bucket(int* __restrict__ histmat,
                                                       int* __restrict__ btot) {
    __shared__ int sd[256];
    int b = blockIdx.x;
    int t = threadIdx.x;
    int e0 = 2 * t, e1 = 2 * t + 1;
    int v0 = (e0 < NBLK) ? histmat[e0 * NB + b] : 0;
    int v1 = (e1 < NBLK) ? histmat[e1 * NB + b] : 0;
    int tsum = v0 + v1;
    sd[t] = tsum;
    __syncthreads();
    for (int off = 1; off < 256; off <<= 1) {
        int x = (t >= off) ? sd[t - off] : 0;
        __syncthreads();
        sd[t] += x;
        __syncthreads();
    }
    int excl = sd[t] - tsum;
    if (e0 < NBLK) histmat[e0 * NB + b] = excl;
    if (e1 < NBLK) histmat[e1 * NB + b] = excl + v0;
    if (t == 255) btot[b] = sd[255];
}

// one block: exclusive scan of bucket totals -> bbase[NB+1]
__global__ __launch_bounds__(512) void csr_btot_scan(const int* __restrict__ btot,
                                                     int* __restrict__ bbase) {
    __shared__ int sd[512];
    int t = threadIdx.x;
    int v = (t < NB) ? btot[t] : 0;
    sd[t] = v;
    __syncthreads();
    for (int off = 1; off < 512; off <<= 1) {
        int x = (t >= off) ? sd[t - off] : 0;
        __syncthreads();
        sd[t] += x;
        __syncthreads();
    }
    int excl = sd[t] - v;
    if (t < NB) bbase[t] = excl;
    if (t == NB - 1) bbase[NB] = excl + v;
}

// each chunk writes part[] into its reserved per-bucket ranges (LDS cursors only)
__global__ __launch_bounds__(256) void csr_scatter(const int* __restrict__ srcs,
                                                   const int* __restrict__ dsts,
                                                   const int* __restrict__ histmat,
                                                   const int* __restrict__ bbase,
                                                   unsigned* __restrict__ part) {
    __shared__ int cur[NB];
    int blk = blockIdx.x;
    for (int t = threadIdx.x; t < NB; t += 256)
        cur[t] = bbase[t] + histmat[blk * NB + t];
    __syncthreads();
    int e0 = blk * CHUNK;
#pragma unroll
    for (int k = 0; k < CHUNK / 256; k++) {
        int e = e0 + k * 256 + threadIdx.x;
        if (e < NE) {
            int s = srcs[e], d = dsts[e];
            int r = atomicAdd(&cur[d >> 8], 1);
            part[r] = (((unsigned)d & 255u) << 24) | (unsigned)s;
        }
    }
}

__global__ __launch_bounds__(256) void bucket_fill(const unsigned* __restrict__ part,
                                                   const int* __restrict__ bbase,
                                                   int* __restrict__ offs,
                                                   int* __restrict__ csr) {
    __shared__ int lcur[256];
    __shared__ int sd[256];
    int b = blockIdx.x;
    int t = threadIdx.x;
    int ebeg = bbase[b], eend = bbase[b + 1];
    int node0 = b << 8;
    int nNodes = min(256, NN - node0);
    lcur[t] = 0;
    __syncthreads();
    for (int e = ebeg + t; e < eend; e += 256) {
        unsigned p = part[e];
        atomicAdd(&lcur[p >> 24], 1);
    }
    __syncthreads();
    int cnt = lcur[t];
    sd[t] = cnt;
    __syncthreads();
    for (int off = 1; off < 256; off <<= 1) {
        int x = (t >= off) ? sd[t - off] : 0;
        __syncthreads();
        sd[t] += x;
        __syncthreads();
    }
    int start = ebeg + sd[t] - cnt;
    if (t < nNodes) offs[node0 + t] = start;
    if (b == NB - 1 && t == 0) offs[NN] = NE;
    lcur[t] = start;
    __syncthreads();
    for (int e = ebeg + t; e < eend; e += 256) {
        unsigned p = part[e];
        int pos = atomicAdd(&lcur[p >> 24], 1);
        csr[pos] = (int)(p & 0xFFFFFFu);
    }
}

// ---------------- fused MFMA GEMM + attention coefficients ----------------

template <int NOUT, int HEADS, bool AF32>
__global__ __launch_bounds__(256) void gemm_fused(
    const float* __restrict__ A32, const unsigned short* __restrict__ A16,
    const float* __restrict__ W, const float* __restrict__ asrc,
    const float* __restrict__ adst, unsigned short* __restrict__ h16out,
    float* __restrict__ als, float* __restrict__ ald, int n) {
    constexpr int NF = NOUT / 16;
    constexpr int PITCH = 136;
    __shared__ unsigned short Wl[NOUT * PITCH];

    const int tid = threadIdx.x;
    for (int i = tid; i < (128 * NOUT) / 4; i += 256) {
        int idx = i * 4;
        int k = idx / NOUT;
        int c = idx - k * NOUT;
        float4 wv = *(const float4*)&W[idx];
        Wl[(c + 0) * PITCH + k] = f2b(wv.x);
        Wl[(c + 1) * PITCH + k] = f2b(wv.y);
        Wl[(c + 2) * PITCH + k] = f2b(wv.z);
        Wl[(c + 3) * PITCH + k] = f2b(wv.w);
    }
    __syncthreads();

    const int lane = tid & 63, wave = tid >> 6;
    const int c = lane & 15, hi = lane >> 4;
    const int r0 = blockIdx.x * 64;
    const int arow = min(r0 + wave * 16 + c, n - 1);
    const int kb = hi * 8;

    f32x4 acc[NF];
#pragma unroll
    for (int nf = 0; nf < NF; ++nf) acc[nf] = 0;

#pragma unroll
    for (int kc = 0; kc < 4; ++kc) {
        bf8v a;
        if constexpr (AF32) {
            const float* ap = A32 + (size_t)arow * 128 + kc * 32 + kb;
            float4 f0 = *(const float4*)ap;
            float4 f1 = *(const float4*)(ap + 4);
            union {
                bf8v v;
                unsigned short u[8];
            } ua;
            ua.u[0] = f2b(f0.x);
            ua.u[1] = f2b(f0.y);
            ua.u[2] = f2b(f0.z);
            ua.u[3] = f2b(f0.w);
            ua.u[4] = f2b(f1.x);
            ua.u[5] = f2b(f1.y);
            ua.u[6] = f2b(f1.z);
            ua.u[7] = f2b(f1.w);
            a = ua.v;
        } else {
            a = *(const bf8v*)(A16 + (size_t)arow * 128 + kc * 32 + kb);
        }
#pragma unroll
        for (int nf = 0; nf < NF; ++nf) {
            bf8v b = *(const bf8v*)&Wl[(nf * 16 + c) * PITCH + kc * 32 + kb];
            acc[nf] = __builtin_amdgcn_mfma_f32_16x16x32_bf16(a, b, acc[nf], 0, 0, 0);
        }
    }

    // epilogue 1: als/ald from accumulators
    float aS[NF], aD[NF];
#pragma unroll
    for (int nf = 0; nf < NF; ++nf) {
        aS[nf] = asrc[nf * 16 + c];
        aD[nf] = adst[nf * 16 + c];
    }
    float sRes[HEADS][4], dRes[HEADS][4];
#pragma unroll
    for (int hh = 0; hh < HEADS; ++hh) {
#pragma unroll
        for (int reg = 0; reg < 4; ++reg) {
            float s = 0.f, d = 0.f;
#pragma unroll
            for (int nf = hh * (NF / HEADS); nf < (hh + 1) * (NF / HEADS); ++nf) {
                s += acc[nf][reg] * aS[nf];
                d += acc[nf][reg] * aD[nf];
            }
#pragma unroll
            for (int o = 1; o < 16; o <<= 1) {
                s += __shfl_xor(s, o);
                d += __shfl_xor(d, o);
            }
            sRes[hh][reg] = s;
            dRes[hh][reg] = d;
        }
    }
    if (c == 0) {
#pragma unroll
        for (int reg = 0; reg < 4; ++reg) {
            int ro = r0 + wave * 16 + hi * 4 + reg;
            if (ro < n) {
                if constexpr (HEADS == 4) {
                    *(float4*)&als[ro * 4] =
                        make_float4(sRes[0][reg], sRes[1][reg], sRes[2][reg], sRes[3][reg]);
                    *(float4*)&ald[ro * 4] =
                        make_float4(dRes[0][reg], dRes[1][reg], dRes[2][reg], dRes[3][reg]);
                } else {
                    als[ro] = sRes[0][reg];
                    ald[ro] = dRes[0][reg];
                }
            }
        }
    }

    // epilogue 2: h -> bf16 via LDS transpose, coalesced store
    __syncthreads();
#pragma unroll
    for (int nf = 0; nf < NF; ++nf) {
#pragma unroll
        for (int reg = 0; reg < 4; ++reg) {
            int rl = wave * 16 + hi * 4 + reg;
            Wl[rl * PITCH + nf * 16 + c] = f2b(acc[nf][reg]);
        }
    }
    __syncthreads();
    constexpr int SEGS = NOUT / 8;
    for (int i = tid; i < 64 * SEGS; i += 256) {
        int rl = i / SEGS, sg = i - rl * SEGS;
        int ro = r0 + rl;
        if (ro < n)
            *(uint4*)&h16out[(size_t)ro * NOUT + sg * 8] =
                *(const uint4*)&Wl[rl * PITCH + sg * 8];
    }
}

// ---------------- GAT aggregation, 4 heads (F=128), wave per dst node ----------------
// Full-wave dword gather (one 256B row per instruction), 8 loads in flight.
// Lane owns feats (2*lane, 2*lane+1); head = lane>>4.

__global__ __launch_bounds__(256) void agg4_kernel(
    const char* __restrict__ hb, const float* __restrict__ als, const float* __restrict__ ald,
    const int* __restrict__ offs, const int* __restrict__ cur, const int* __restrict__ csr,
    const float* __restrict__ bias, __hip_bfloat16* __restrict__ out, int n, int do_l1) {
    __shared__ int soff[4][64];
    __shared__ float sp[4][64][4];
    int w = threadIdx.x >> 6;
    int v = blockIdx.x * 4 + w;
    if (v >= n) return;
    int lane = threadIdx.x & 63;
    int hd = lane >> 4;
    int lane4 = lane << 2;

    float4 av = *(const float4*)&ald[v * 4];
    float4 svv = *(const float4*)&als[v * 4];
    int begin = offs[v], end = cur[v];

    float ps0 = __expf(lrelu(svv.x + av.x, 0.2f));
    float ps1 = __expf(lrelu(svv.y + av.y, 0.2f));
    float ps2 = __expf(lrelu(svv.z + av.z, 0.2f));
    float ps3 = __expf(lrelu(svv.w + av.w, 0.2f));
    float psel = hd == 0 ? ps0 : hd == 1 ? ps1 : hd == 2 ? ps2 : ps3;
    unsigned uv = *(const unsigned*)(hb + (size_t)v * 256 + lane4);
    float acc0 = psel * blo(uv);
    float acc1 = psel * bhi(uv);
    float s0 = 0.f, s1 = 0.f, s2 = 0.f, s3 = 0.f;

    for (int base = begin; base < end; base += 64) {
        int idx = base + lane;
        int cnt = min(64, end - base);
        if (idx < end) {
            int s = csr[idx];
            float4 q = *(const float4*)&als[s * 4];
            float p0 = __expf(lrelu(q.x + av.x, 0.2f));
            float p1 = __expf(lrelu(q.y + av.y, 0.2f));
            float p2 = __expf(lrelu(q.z + av.z, 0.2f));
            float p3 = __expf(lrelu(q.w + av.w, 0.2f));
            soff[w][lane] = s << 8;  // byte offset into bf16 rows (128*2B)
            sp[w][lane][0] = p0;
            sp[w][lane][1] = p1;
            sp[w][lane][2] = p2;
            sp[w][lane][3] = p3;
            s0 += p0; s1 += p1; s2 += p2; s3 += p3;
        }
        asm volatile("s_waitcnt lgkmcnt(0)" ::: "memory");
        int t = 0;
        for (; t + 8 <= cnt; t += 8) {
            int o0 = soff[w][t + 0], o1 = soff[w][t + 1];
            int o2 = soff[w][t + 2], o3 = soff[w][t + 3];
            int o4 = soff[w][t + 4], o5 = soff[w][t + 5];
            int o6 = soff[w][t + 6], o7 = soff[w][t + 7];
            float p0 = sp[w][t + 0][hd], p1 = sp[w][t + 1][hd];
            float p2 = sp[w][t + 2][hd], p3 = sp[w][t + 3][hd];
            float p4 = sp[w][t + 4][hd], p5 = sp[w][t + 5][hd];
            float p6 = sp[w][t + 6][hd], p7 = sp[w][t + 7][hd];
            unsigned u0 = *(const unsigned*)(hb + o0 + lane4);
            unsigned u1 = *(const unsigned*)(hb + o1 + lane4);
            unsigned u2 = *(const unsigned*)(hb + o2 + lane4);
            unsigned u3 = *(const unsigned*)(hb + o3 + lane4);
            unsigned u4 = *(const unsigned*)(hb + o4 + lane4);
            unsigned u5 = *(const unsigned*)(hb + o5 + lane4);
            unsigned u6 = *(const unsigned*)(hb + o6 + lane4);
            unsigned u7 = *(const unsigned*)(hb + o7 + lane4);
            acc0 += p0 * blo(u0);
            acc1 += p0 * bhi(u0);
            acc0 += p1 * blo(u1);
            acc1 += p1 * bhi(u1);
            acc0 += p2 * blo(u2);
            acc1 += p2 * bhi(u2);
            acc0 += p3 * blo(u3);
            acc1 += p3 * bhi(u3);
            acc0 += p4 * blo(u4);
            acc1 += p4 * bhi(u4);
            acc0 += p5 * blo(u5);
            acc1 += p5 * bhi(u5);
            acc0 += p6 * blo(u6);
            acc1 += p6 * bhi(u6);
            acc0 += p7 * blo(u7);
            acc1 += p7 * bhi(u7);
        }
        for (; t < cnt; ++t) {
            int oa = soff[w][t];
            float pa = sp[w][t][hd];
            unsigned ua = *(const unsigned*)(hb + oa + lane4);
            acc0 += pa * blo(ua);
            acc1 += pa * bhi(ua);
        }
    }
#pragma unroll
    for (int o = 32; o > 0; o >>= 1) {
        s0 += __shfl_xor(s0, o);
        s1 += __shfl_xor(s1, o);
        s2 += __shfl_xor(s2, o);
        s3 += __shfl_xor(s3, o);
    }
    s0 += ps0; s1 += ps1; s2 += ps2; s3 += ps3;
    float ssel = hd == 0 ? s0 : hd == 1 ? s1 : hd == 2 ? s2 : s3;
    float inv = 1.f / (ssel + 1e-16f);
    float2 bv = *(const float2*)&bias[2 * lane];
    float o0 = lrelu(acc0 * inv + bv.x, 0.01f);
    float o1 = lrelu(acc1 * inv + bv.y, 0.01f);
    if (do_l1) {
        float t = fabsf(o0) + fabsf(o1);
#pragma unroll
        for (int o = 32; o > 0; o >>= 1) t += __shfl_xor(t, o);
        float li = 1.f / fmaxf(t, 1e-12f);
        o0 *= li;
        o1 *= li;
    }
    bh2 pk;
    pk.x = __float2bfloat16(o0);
    pk.y = __float2bfloat16(o1);
    *(bh2*)&out[(size_t)v * 128 + 2 * lane] = pk;
}

// ---------------- GAT aggregation, 1 head (F=64), wave per dst node --------

__global__ __launch_bounds__(256) void agg1_kernel(
    const char* __restrict__ hb, const float* __restrict__ als, const float* __restrict__ ald,
    const int* __restrict__ offs, const int* __restrict__ cur, const int* __restrict__ csr,
    const float* __restrict__ bias, float* __restrict__ out, int n) {
    __shared__ int soff[4][64];
    __shared__ float sp[4][64];
    int w = threadIdx.x >> 6;
    int v = blockIdx.x * 4 + w;
    if (v >= n) return;
    int lane = threadIdx.x & 63;
    int lane2 = lane << 1;
    float aldv = ald[v];
    float alsv = als[v];
    int begin = offs[v], end = cur[v];

    float pself = __expf(lrelu(alsv + aldv, 0.2f));
    unsigned short usv = *(const unsigned short*)(hb + (size_t)v * 128 + lane2);
    float acc = pself * __uint_as_float(((unsigned)usv) << 16);
    float ssum = 0.f;

    for (int base = begin; base < end; base += 64) {
        int idx = base + lane;
        int cnt = min(64, end - base);
        if (idx < end) {
            int s = csr[idx];
            float p = __expf(lrelu(als[s] + aldv, 0.2f));
            soff[w][lane] = s << 7;  // byte offset into bf16 rows (64*2B)
            sp[w][lane] = p;
            ssum += p;
        }
        asm volatile("s_waitcnt lgkmcnt(0)" ::: "memory");
        int t = 0;
        for (; t + 8 <= cnt; t += 8) {
            int o0 = soff[w][t + 0], o1 = soff[w][t + 1];
            int o2 = soff[w][t + 2], o3 = soff[w][t + 3];
            int o4 = soff[w][t + 4], o5 = soff[w][t + 5];
            int o6 = soff[w][t + 6], o7 = soff[w][t + 7];
            float p0 = sp[w][t + 0], p1 = sp[w][t + 1];
            float p2 = sp[w][t + 2], p3 = sp[w][t + 3];
            float p4 = sp[w][t + 4], p5 = sp[w][t + 5];
            float p6 = sp[w][t + 6], p7 = sp[w][t + 7];
            unsigned short u0 = *(const unsigned short*)(hb + o0 + lane2);
            unsigned short u1 = *(const unsigned short*)(hb + o1 + lane2);
            unsigned short u2 = *(const unsigned short*)(hb + o2 + lane2);
            unsigned short u3 = *(const unsigned short*)(hb + o3 + lane2);
            unsigned short u4 = *(const unsigned short*)(hb + o4 + lane2);
            unsigned short u5 = *(const unsigned short*)(hb + o5 + lane2);
            unsigned short u6 = *(const unsigned short*)(hb + o6 + lane2);
            unsigned short u7 = *(const unsigned short*)(hb + o7 + lane2);
            acc += p0 * __uint_as_float(((unsigned)u0) << 16);
            acc += p1 * __uint_as_float(((unsigned)u1) << 16);
            acc += p2 * __uint_as_float(((unsigned)u2) << 16);
            acc += p3 * __uint_as_float(((unsigned)u3) << 16);
            acc += p4 * __uint_as_float(((unsigned)u4) << 16);
            acc += p5 * __uint_as_float(((unsigned)u5) << 16);
            acc += p6 * __uint_as_float(((unsigned)u6) << 16);
            acc += p7 * __uint_as_float(((unsigned)u7) << 16);
        }
        for (; t < cnt; ++t) {
            int oa = soff[w][t];
            float pa = sp[w][t];
            unsigned short ua = *(const unsigned short*)(hb + oa + lane2);
            acc += pa * __uint_as_float(((unsigned)ua) << 16);
        }
    }
#pragma unroll
    for (int o = 32; o > 0; o >>= 1) ssum += __shfl_xor(ssum, o);
    ssum += pself;
    float o = acc / (ssum + 1e-16f) + bias[lane];
    float t = fabsf(o);
#pragma unroll
    for (int off = 32; off > 0; off >>= 1) t += __shfl_xor(t, off);
    o = o / fmaxf(t, 1e-12f);
    out[(size_t)v * 64 + lane] = fmaxf(o, 0.f);
}

// ---------------- launch ----------------

extern "C" void kernel_launch(void* const* d_in, const int* in_sizes, int n_in,
                              void* d_out, int out_size, void* d_ws, size_t ws_size,
                              hipStream_t stream) {
    const float* x = (const float*)d_in[0];
    const int* ei = (const int*)d_in[1];
    const float* W0 = (const float*)d_in[2];
    const float* b0 = (const float*)d_in[3];
    const float* as0 = (const float*)d_in[4];
    const float* ad0 = (const float*)d_in[5];
    const float* W1 = (const float*)d_in[6];
    const float* b1 = (const float*)d_in[7];
    const float* as1 = (const float*)d_in[8];
    const float* ad1 = (const float*)d_in[9];
    const float* W2 = (const float*)d_in[10];
    const float* b2 = (const float*)d_in[11];
    const float* as2 = (const float*)d_in[12];
    const float* ad2 = (const float*)d_in[13];
    float* outp = (float*)d_out;

    char* ws = (char*)d_ws;
    size_t off = 0;
    auto alloc = [&](size_t bytes) -> void* {
        void* p = ws + off;
        off = (off + bytes + 255) & ~(size_t)255;
        return p;
    };
    int* offs = (int*)alloc((NN + 1) * 4);
    int* histmat = (int*)alloc((size_t)NBLK * NB * 4);
    int* btot = (int*)alloc(NB * 4);
    int* bbase = (int*)alloc((NB + 1) * 4);
    unsigned* part = (unsigned*)alloc((size_t)NE * 4);
    int* csr = (int*)alloc((size_t)NE * 4);
    unsigned short* h16 = (unsigned short*)alloc((size_t)NN * 128 * 2);
    unsigned short* a16 = (unsigned short*)alloc((size_t)NN * 128 * 2);
    float* als = (float*)alloc(NN * 4 * 4);
    float* ald = (float*)alloc(NN * 4 * 4);

    const int* srcs = ei;
    const int* dsts = ei + NE;

    // CSR build (atomic-free two-phase counting sort, parallel scans)
    csr_count<<<NBLK, 256, 0, stream>>>(dsts, histmat);
    csr_scan_bucket<<<NB, 256, 0, stream>>>(histmat, btot);
    csr_btot_scan<<<1, 512, 0, stream>>>(btot, bbase);
    csr_scatter<<<NBLK, 256, 0, stream>>>(srcs, dsts, histmat, bbase, part);
    bucket_fill<<<NB, 256, 0, stream>>>(part, bbase, offs, csr);

    int ggrid = (NN + 63) / 64;
    int aggrid = (NN + 3) / 4;

    // layer 0
    gemm_fused<128, 4, true><<<ggrid, 256, 0, stream>>>(x, nullptr, W0, as0, ad0, h16, als, ald,
                                                        NN);
    agg4_kernel<<<aggrid, 256, 0, stream>>>((const char*)h16, als, ald, offs, offs + 1, csr, b0,
                                            (__hip_bfloat16*)a16, NN, 1);
    // layer 1
    gemm_fused<128, 4, false><<<ggrid, 256, 0, stream>>>(nullptr, a16, W1, as1, ad1, h16, als,
                                                         ald, NN);
    agg4_kernel<<<aggrid, 256, 0, stream>>>((const char*)h16, als, ald, offs, offs + 1, csr, b1,
                                            (__hip_bfloat16*)a16, NN, 0);
    // layer 2
    gemm_fused<64, 1, false><<<ggrid, 256, 0, stream>>>(nullptr, a16, W2, as2, ad2, h16, als,
                                                        ald, NN);
    agg1_kernel<<<aggrid, 256, 0, stream>>>((const char*)h16, als, ald, offs, offs + 1, csr, b2,
                                            outp, NN);
}